// Round 2
// baseline (1239.571 us; speedup 1.0000x reference)
//
#include <hip/hip_runtime.h>
#include <hip/hip_bf16.h>

// MultiTokenPrediction: main head logits + fused CE for main + 2 aux heads.
// B=1, S=2048, D=1024, V=50257, heads predict t+1 (main), t+2, t+3 (aux).

typedef __hip_bfloat16 bf16;
typedef __attribute__((ext_vector_type(8))) short bf16x8;
typedef __attribute__((ext_vector_type(4))) float f32x4;

typedef const __attribute__((address_space(1))) void* gptr_t;
typedef __attribute__((address_space(3))) void* lptr_t;

#define S_LEN   2048
#define DMODEL  1024
#define VOCAB   50257
#define VPAD2   50432   // 197*256
#define NT256   197     // VPAD2/256

__device__ __forceinline__ void gload_lds16(const void* g, void* l) {
  __builtin_amdgcn_global_load_lds((gptr_t)g, (lptr_t)l, 16, 0, 0);
}

// ---------------- f32 -> bf16 conversion with row zero-padding ----------------
__global__ __launch_bounds__(256) void k_cvt(const float* __restrict__ src,
                                             bf16* __restrict__ dst,
                                             long rows_src, long rows_pad) {
  const long total4 = rows_pad << 8;  // rows_pad * 1024 / 4
  for (long i = (long)blockIdx.x * 256 + threadIdx.x; i < total4;
       i += (long)gridDim.x * 256) {
    const long e = i << 2;
    const long row = e >> 10;
    alignas(8) bf16 o[4];
    if (row < rows_src) {
      const float4 v = *(const float4*)(src + e);
      o[0] = __float2bfloat16(v.x); o[1] = __float2bfloat16(v.y);
      o[2] = __float2bfloat16(v.z); o[3] = __float2bfloat16(v.w);
    } else {
      o[0] = o[1] = o[2] = o[3] = __float2bfloat16(0.f);
    }
    *(uint2*)(dst + e) = *(const uint2*)o;
  }
}

// ---------------- RMSNorm row kernel: f32 in, bf16 out ----------------
__global__ __launch_bounds__(256) void k_rms(const float* __restrict__ x,
                                             const float* __restrict__ w,
                                             bf16* __restrict__ xn) {
  const int row = blockIdx.x;
  const int t = threadIdx.x;
  const float4 v = ((const float4*)(x + (size_t)row * DMODEL))[t];
  float ss = v.x*v.x + v.y*v.y + v.z*v.z + v.w*v.w;
  #pragma unroll
  for (int d = 1; d < 64; d <<= 1) ss += __shfl_xor(ss, d, 64);
  __shared__ float red[4];
  if ((t & 63) == 0) red[t >> 6] = ss;
  __syncthreads();
  const float tot = red[0] + red[1] + red[2] + red[3];
  const float scale = rsqrtf(tot * (1.f / DMODEL) + 1e-5f);
  const float4 wv = ((const float4*)w)[t];
  alignas(8) bf16 o[4];
  o[0] = __float2bfloat16(v.x * scale * wv.x);
  o[1] = __float2bfloat16(v.y * scale * wv.y);
  o[2] = __float2bfloat16(v.z * scale * wv.z);
  o[3] = __float2bfloat16(v.w * scale * wv.w);
  *(uint2*)(xn + (size_t)row * DMODEL + t * 4) = *(const uint2*)o;
}

// ============ 256x256 8-phase bf16 MFMA GEMM, optional fused CE ============
// C[m][n] = sum_k A[m][k]*B[n][k]. A:[2048][1024], B:[VPAD2][1024] bf16.
// grid(8, NT256) (bm fastest for B-tile sharing), block 512 (8 waves, 2Mx4N).
// LDS: 2 buffers x {A-k0, B-k0, A-k1, B-k1} halves of 16KB each.
// Half layout: [256 rows][32 cols bf16] as 16 subtiles of [16][32] (1KB),
//   byte(r,c) = (r>>4)*1024 + (r&15)*64 + (c&31)*2  -> b128 frag reads are
//   conflict-free (bank floor), and global_load_lds dest stays linear.
template<bool WRITE_OUT, bool DO_CE>
__global__ __launch_bounds__(512, 2)
void k_gemm256(const bf16* __restrict__ A, const bf16* __restrict__ B,
               float* __restrict__ C, long ldc, int Nvalid,
               const int* __restrict__ targets, int shift,
               float* __restrict__ pmax, float* __restrict__ psum,
               float* __restrict__ ptgt, int ntiles) {
  __shared__ char lds[131072 + 9216];

  const int t = threadIdx.x;
  const int w = t >> 6, l = t & 63;
  const int g = l >> 4, q = l & 15;
  const int wr = w >> 2, wc = w & 3;
  const int bm = blockIdx.x, bn = blockIdx.y;

  f32x4 acc[8][4];
  #pragma unroll
  for (int i = 0; i < 8; ++i)
    #pragma unroll
    for (int j = 0; j < 4; ++j)
      #pragma unroll
      for (int r = 0; r < 4; ++r) acc[i][j][r] = 0.f;

  // staging source pointers (per-lane). chunk c2 = w*2+j covers subtile c2.
  const int srow = (l >> 2);          // row within 16-row subtile
  const int scol = (l & 3) * 8;       // col group within 32-col subtile
  const bf16* gA0 = A + (size_t)(bm * 256 + (w * 2 + 0) * 16 + srow) * DMODEL + scol;
  const bf16* gA1 = A + (size_t)(bm * 256 + (w * 2 + 1) * 16 + srow) * DMODEL + scol;
  const bf16* gB0 = B + (size_t)(bn * 256 + (w * 2 + 0) * 16 + srow) * DMODEL + scol;
  const bf16* gB1 = B + (size_t)(bn * 256 + (w * 2 + 1) * 16 + srow) * DMODEL + scol;

  // stage half h (0=A-k0,1=B-k0,2=A-k1,3=B-k1) of K-tile tt into buffer buf
  auto stage = [&](int buf, int h, int tt) {
    const int kbase = tt * 64 + (h >> 1) * 32;
    char* lb = lds + buf * 65536 + (h >> 1) * 32768 + (h & 1) * 16384 + (w * 2) * 1024;
    if (h & 1) {
      gload_lds16(gB0 + kbase, lb);
      gload_lds16(gB1 + kbase, lb + 1024);
    } else {
      gload_lds16(gA0 + kbase, lb);
      gload_lds16(gA1 + kbase, lb + 1024);
    }
  };

  const int laneoff = q * 64 + g * 16;  // within-subtile byte for frag reads
  auto lda = [&](int buf, int kk, int mi) {
    return *(const bf16x8*)(lds + buf * 65536 + kk * 32768 + (wr * 8 + mi) * 1024 + laneoff);
  };
  auto ldb = [&](int buf, int kk, int ni) {
    return *(const bf16x8*)(lds + buf * 65536 + kk * 32768 + 16384 + (wc * 4 + ni) * 1024 + laneoff);
  };

  // ---- prologue: stage tile 0 fully; make k0-halves visible ----
  stage(0, 0, 0); stage(0, 1, 0); stage(0, 2, 0); stage(0, 3, 0);
  asm volatile("s_waitcnt vmcnt(4)" ::: "memory");
  __builtin_amdgcn_s_barrier();
  __builtin_amdgcn_sched_barrier(0);

  #define PHASE_MFMA(MH, KK)                                                     \
    __builtin_amdgcn_s_barrier();                                                \
    __builtin_amdgcn_sched_barrier(0);                                           \
    __builtin_amdgcn_s_setprio(1);                                               \
    _Pragma("unroll")                                                            \
    for (int mi = 0; mi < 4; ++mi)                                               \
      _Pragma("unroll")                                                          \
      for (int ni = 0; ni < 4; ++ni)                                             \
        acc[(MH)*4 + mi][ni] = __builtin_amdgcn_mfma_f32_16x16x32_bf16(          \
            a[mi], b[ni], acc[(MH)*4 + mi][ni], 0, 0, 0);                        \
    __builtin_amdgcn_s_setprio(0);                                               \
    __builtin_amdgcn_sched_barrier(0);

  for (int tt = 0; tt < 16; ++tt) {
    const int buf = tt & 1, nbuf = buf ^ 1;
    const bool pre = tt < 15;
    bf16x8 a[4], b[4];

    // ---- P0: kk0, mi 0-3 ----
    #pragma unroll
    for (int mi = 0; mi < 4; ++mi) a[mi] = lda(buf, 0, mi);
    #pragma unroll
    for (int ni = 0; ni < 4; ++ni) b[ni] = ldb(buf, 0, ni);
    if (pre) stage(nbuf, 0, tt + 1);
    PHASE_MFMA(0, 0)
    __builtin_amdgcn_s_barrier();
    __builtin_amdgcn_sched_barrier(0);

    // ---- P1: kk0, mi 4-7 ----
    #pragma unroll
    for (int mi = 0; mi < 4; ++mi) a[mi] = lda(buf, 0, 4 + mi);
    if (pre) stage(nbuf, 1, tt + 1);
    PHASE_MFMA(1, 0)
    if (pre) asm volatile("s_waitcnt vmcnt(4)" ::: "memory");   // k1-halves(tt) landed
    else     asm volatile("s_waitcnt vmcnt(0)" ::: "memory");   // epilogue drain
    __builtin_amdgcn_s_barrier();
    __builtin_amdgcn_sched_barrier(0);

    // ---- P2: kk1, mi 0-3 ----
    #pragma unroll
    for (int mi = 0; mi < 4; ++mi) a[mi] = lda(buf, 1, mi);
    #pragma unroll
    for (int ni = 0; ni < 4; ++ni) b[ni] = ldb(buf, 1, ni);
    if (pre) stage(nbuf, 2, tt + 1);
    PHASE_MFMA(0, 1)
    __builtin_amdgcn_s_barrier();
    __builtin_amdgcn_sched_barrier(0);

    // ---- P3: kk1, mi 4-7 ----
    #pragma unroll
    for (int mi = 0; mi < 4; ++mi) a[mi] = lda(buf, 1, 4 + mi);
    if (pre) stage(nbuf, 3, tt + 1);
    PHASE_MFMA(1, 1)
    if (pre) asm volatile("s_waitcnt vmcnt(4)" ::: "memory");   // k0-halves(tt+1) landed
    __builtin_amdgcn_s_barrier();
    __builtin_amdgcn_sched_barrier(0);
  }
  #undef PHASE_MFMA

  // ---------------- epilogue ----------------
  if constexpr (WRITE_OUT) {
    #pragma unroll
    for (int mi = 0; mi < 8; ++mi) {
      #pragma unroll
      for (int r = 0; r < 4; ++r) {
        const long row = bm * 256 + wr * 128 + mi * 16 + g * 4 + r;
        #pragma unroll
        for (int ni = 0; ni < 4; ++ni) {
          const int col = bn * 256 + wc * 64 + ni * 16 + q;
          if (col < Nvalid) C[row * ldc + col] = acc[mi][ni][r];
        }
      }
    }
  }

  if constexpr (DO_CE) {
    float* lds_m = (float*)(lds + 131072);   // [256][4]
    float* lds_s = lds_m + 1024;             // [256][4]
    int* lds_tgt = (int*)(lds_s + 1024);     // [256]
    if (t < 256) {
      const int rowg = bm * 256 + t;
      lds_tgt[t] = (rowg < S_LEN - shift) ? targets[rowg + shift] : -1;
    }
    __syncthreads();
    #pragma unroll
    for (int mi = 0; mi < 8; ++mi) {
      #pragma unroll
      for (int r = 0; r < 4; ++r) {
        const int rl = wr * 128 + mi * 16 + g * 4 + r;
        const int tgt = lds_tgt[rl];
        float v[4];
        #pragma unroll
        for (int ni = 0; ni < 4; ++ni) {
          const int n = bn * 256 + wc * 64 + ni * 16 + q;
          const float av = acc[mi][ni][r];
          if (n == tgt) ptgt[bm * 256 + rl] = av;
          v[ni] = (n < Nvalid) ? av : -1e30f;
        }
        float m = fmaxf(fmaxf(v[0], v[1]), fmaxf(v[2], v[3]));
        #pragma unroll
        for (int d = 1; d < 16; d <<= 1) m = fmaxf(m, __shfl_xor(m, d, 64));
        float s = 0.f;
        #pragma unroll
        for (int ni = 0; ni < 4; ++ni) s += __expf(v[ni] - m);
        #pragma unroll
        for (int d = 1; d < 16; d <<= 1) s += __shfl_xor(s, d, 64);
        if (q == 0) { lds_m[rl * 4 + wc] = m; lds_s[rl * 4 + wc] = s; }
      }
    }
    __syncthreads();
    if (t < 256) {
      float M = lds_m[t * 4 + 0], Ssum = lds_s[t * 4 + 0];
      #pragma unroll
      for (int c = 1; c < 4; ++c) {
        const float m2 = lds_m[t * 4 + c], s2 = lds_s[t * 4 + c];
        const float nM = fmaxf(M, m2);
        Ssum = Ssum * __expf(M - nM) + s2 * __expf(m2 - nM);
        M = nM;
      }
      const size_t idx = (size_t)(bm * 256 + t) * ntiles + bn;
      pmax[idx] = M;
      psum[idx] = Ssum;
    }
  }
}

// ---------------- 128x128 GEMM (kept for the small d->d projection) ----------------
__global__ __launch_bounds__(256, 2)
void k_gemm(const bf16* __restrict__ A, const bf16* __restrict__ B,
            float* __restrict__ C, long ldc, int Nvalid) {
  constexpr int K = DMODEL;
  __shared__ bf16 As[128 * 32];
  __shared__ bf16 Bs[128 * 32];

  const int t = threadIdx.x;
  const int bn = blockIdx.x, bm = blockIdx.y;
  const int w = t >> 6, l = t & 63, g = l >> 4, q = l & 15;
  const int wr = w >> 1, wc = w & 1;

  f32x4 acc[4][4];
  #pragma unroll
  for (int i = 0; i < 4; ++i)
    #pragma unroll
    for (int j = 0; j < 4; ++j)
      #pragma unroll
      for (int r = 0; r < 4; ++r) acc[i][j][r] = 0.f;

  char* lA0 = (char*)As + w * 1024;
  char* lA1 = (char*)As + 4096 + w * 1024;
  char* lB0 = (char*)Bs + w * 1024;
  char* lB1 = (char*)Bs + 4096 + w * 1024;
  const char* gA0 = (const char*)(A + (size_t)(bm * 128 + (t >> 2)) * K) + (t & 3) * 16;
  const char* gA1 = gA0 + (size_t)64 * K * 2;
  const char* gB0 = (const char*)(B + (size_t)(bn * 128 + (t >> 2)) * K) + (t & 3) * 16;
  const char* gB1 = gB0 + (size_t)64 * K * 2;

  for (int k0 = 0; k0 < K; k0 += 32) {
    const int kb = k0 * 2;
    gload_lds16(gA0 + kb, lA0);
    gload_lds16(gA1 + kb, lA1);
    gload_lds16(gB0 + kb, lB0);
    gload_lds16(gB1 + kb, lB1);
    __syncthreads();
    bf16x8 a[4], b[4];
    #pragma unroll
    for (int mi = 0; mi < 4; ++mi)
      a[mi] = *(const bf16x8*)&As[(wr * 64 + mi * 16 + q) * 32 + g * 8];
    #pragma unroll
    for (int ni = 0; ni < 4; ++ni)
      b[ni] = *(const bf16x8*)&Bs[(wc * 64 + ni * 16 + q) * 32 + g * 8];
    #pragma unroll
    for (int mi = 0; mi < 4; ++mi)
      #pragma unroll
      for (int ni = 0; ni < 4; ++ni)
        acc[mi][ni] = __builtin_amdgcn_mfma_f32_16x16x32_bf16(a[mi], b[ni], acc[mi][ni], 0, 0, 0);
    __syncthreads();
  }

  #pragma unroll
  for (int mi = 0; mi < 4; ++mi) {
    #pragma unroll
    for (int r = 0; r < 4; ++r) {
      const long row = bm * 128 + wr * 64 + mi * 16 + g * 4 + r;
      #pragma unroll
      for (int ni = 0; ni < 4; ++ni) {
        const int col = bn * 128 + wc * 64 + ni * 16 + q;
        if (col < Nvalid) C[row * ldc + col] = acc[mi][ni][r];
      }
    }
  }
}

// ---------------- combine per-row partials -> NLL ----------------
__global__ __launch_bounds__(64) void k_combine(const float* __restrict__ pmax,
                                                const float* __restrict__ psum,
                                                const float* __restrict__ ptgt,
                                                float* __restrict__ nll,
                                                int ntiles, int nv) {
  const int r = blockIdx.x;
  const int l = threadIdx.x;
  float M = -1e30f, Ssum = 0.f;
  for (int tl = l; tl < ntiles; tl += 64) {
    const float m = pmax[(size_t)r * ntiles + tl];
    const float s = psum[(size_t)r * ntiles + tl];
    const float nM = fmaxf(M, m);
    Ssum = Ssum * __expf(M - nM) + s * __expf(m - nM);
    M = nM;
  }
  #pragma unroll
  for (int d = 1; d < 64; d <<= 1) {
    const float m2 = __shfl_xor(M, d, 64);
    const float s2 = __shfl_xor(Ssum, d, 64);
    const float nM = fmaxf(M, m2);
    Ssum = Ssum * __expf(M - nM) + s2 * __expf(m2 - nM);
    M = nM;
  }
  if (l == 0) nll[r] = (r < nv) ? (M + logf(Ssum) - ptgt[r]) : 0.f;
}

// ---------------- final loss ----------------
__global__ __launch_bounds__(256) void k_loss(const float* __restrict__ nll,
                                              float* __restrict__ out) {
  __shared__ float sh[256];
  const int t = threadIdx.x;
  float sums[3];
  #pragma unroll
  for (int h = 0; h < 3; ++h) {
    const int nv = 2047 - h;
    float s = 0.f;
    for (int r = t; r < nv; r += 256) s += nll[h * 2048 + r];
    sh[t] = s; __syncthreads();
    for (int off = 128; off > 0; off >>= 1) {
      if (t < off) sh[t] += sh[t + off];
      __syncthreads();
    }
    sums[h] = sh[0]; __syncthreads();
  }
  if (t == 0)
    out[0] = sums[0] / 2047.f + 0.3f * 0.5f * (sums[1] / 2046.f + sums[2] / 2045.f);
}

extern "C" void kernel_launch(void* const* d_in, const int* in_sizes, int n_in,
                              void* d_out, int out_size, void* d_ws, size_t ws_size,
                              hipStream_t stream) {
  const float* hidden      = (const float*)d_in[0];
  const int*   targets     = (const int*)d_in[1];
  const float* emb_w       = (const float*)d_in[2];
  const float* main_norm_w = (const float*)d_in[3];
  const float* aux_proj_w  = (const float*)d_in[4];
  const float* aux_norm_w  = (const float*)d_in[5];
  const float* aux_out_w   = (const float*)d_in[6];
  float* out = (float*)d_out;

  char* ws = (char*)d_ws;
  // workspace layout
  bf16*  Wb    = (bf16*)(ws);                   // [VPAD2][1024] bf16, 103,284,736 B
  bf16*  hb    = (bf16*)(ws + 103284736);       // hidden bf16, 4 MiB
  bf16*  xn    = (bf16*)(ws + 107479040);       // normalized input bf16, 4 MiB
  bf16*  projb = (bf16*)(ws + 111673344);       // aux proj weights bf16, 4 MiB
  float* hbuf  = (float*)(ws + 115867648);      // aux pre-norm f32, 8 MiB
  float* pmax  = (float*)(ws + 124256256);      // [2048][197]
  float* psum  = (float*)(ws + 125870080);      // [2048][197]
  float* ptgt  = (float*)(ws + 127483904);      // [2048]
  float* nll   = (float*)(ws + 127492096);      // [3][2048]

  // prep
  k_cvt<<<2048, 256, 0, stream>>>(hidden, hb, 2048, 2048);
  k_cvt<<<2048, 256, 0, stream>>>(aux_proj_w, projb, 2048, 2048);
  k_rms<<<2048, 256, 0, stream>>>(hidden, main_norm_w, xn);

  // ---- main head ----
  k_cvt<<<2048, 256, 0, stream>>>(emb_w, Wb, VOCAB, VPAD2);
  k_gemm256<true, true><<<dim3(8, NT256), 512, 0, stream>>>(
      xn, Wb, out, VOCAB, VOCAB, targets, 1, pmax, psum, ptgt, NT256);
  k_combine<<<2048, 64, 0, stream>>>(pmax, psum, ptgt, nll, NT256, 2047);

  // ---- aux heads ----
  for (int i = 0; i < 2; ++i) {
    k_cvt<<<2048, 256, 0, stream>>>(aux_out_w + (size_t)i * VOCAB * DMODEL, Wb, VOCAB, VPAD2);
    k_gemm<<<dim3(8, 16), 256, 0, stream>>>(
        hb, projb + (size_t)i * DMODEL * DMODEL, hbuf, DMODEL, DMODEL);
    k_rms<<<2048, 256, 0, stream>>>(hbuf, aux_norm_w + (size_t)i * DMODEL, xn);
    k_gemm256<false, true><<<dim3(8, NT256), 512, 0, stream>>>(
        xn, Wb, nullptr, 0, VOCAB, targets, i + 2, pmax, psum, ptgt, NT256);
    k_combine<<<2048, 64, 0, stream>>>(pmax, psum, ptgt, nll + (i + 1) * 2048, NT256, 2048 - (i + 2));
  }

  k_loss<<<1, 256, 0, stream>>>(nll, out + (size_t)S_LEN * VOCAB);
}

// Round 3
// 1208.513 us; speedup vs baseline: 1.0257x; 1.0257x over previous
//
#include <hip/hip_runtime.h>
#include <hip/hip_bf16.h>

// MultiTokenPrediction: main head logits + fused CE for main + 2 aux heads.
// B=1, S=2048, D=1024, V=50257, heads predict t+1 (main), t+2, t+3 (aux).

typedef __hip_bfloat16 bf16;
typedef __attribute__((ext_vector_type(8))) short bf16x8;
typedef __attribute__((ext_vector_type(4))) float f32x4;

typedef const __attribute__((address_space(1))) void* gptr_t;
typedef __attribute__((address_space(3))) void* lptr_t;

#define S_LEN   2048
#define DMODEL  1024
#define VOCAB   50257
#define VPAD2   50432   // 197*256
#define NT256   197     // VPAD2/256

__device__ __forceinline__ void gload_lds16(const void* g, void* l) {
  __builtin_amdgcn_global_load_lds((gptr_t)g, (lptr_t)l, 16, 0, 0);
}

// ---------------- f32 -> bf16 conversion with row zero-padding ----------------
__global__ __launch_bounds__(256) void k_cvt(const float* __restrict__ src,
                                             bf16* __restrict__ dst,
                                             long rows_src, long rows_pad) {
  const long total4 = rows_pad << 8;  // rows_pad * 1024 / 4
  for (long i = (long)blockIdx.x * 256 + threadIdx.x; i < total4;
       i += (long)gridDim.x * 256) {
    const long e = i << 2;
    const long row = e >> 10;
    alignas(8) bf16 o[4];
    if (row < rows_src) {
      const float4 v = *(const float4*)(src + e);
      o[0] = __float2bfloat16(v.x); o[1] = __float2bfloat16(v.y);
      o[2] = __float2bfloat16(v.z); o[3] = __float2bfloat16(v.w);
    } else {
      o[0] = o[1] = o[2] = o[3] = __float2bfloat16(0.f);
    }
    *(uint2*)(dst + e) = *(const uint2*)o;
  }
}

// ---------------- RMSNorm row kernel: f32 in, bf16 out ----------------
__global__ __launch_bounds__(256) void k_rms(const float* __restrict__ x,
                                             const float* __restrict__ w,
                                             bf16* __restrict__ xn) {
  const int row = blockIdx.x;
  const int t = threadIdx.x;
  const float4 v = ((const float4*)(x + (size_t)row * DMODEL))[t];
  float ss = v.x*v.x + v.y*v.y + v.z*v.z + v.w*v.w;
  #pragma unroll
  for (int d = 1; d < 64; d <<= 1) ss += __shfl_xor(ss, d, 64);
  __shared__ float red[4];
  if ((t & 63) == 0) red[t >> 6] = ss;
  __syncthreads();
  const float tot = red[0] + red[1] + red[2] + red[3];
  const float scale = rsqrtf(tot * (1.f / DMODEL) + 1e-5f);
  const float4 wv = ((const float4*)w)[t];
  alignas(8) bf16 o[4];
  o[0] = __float2bfloat16(v.x * scale * wv.x);
  o[1] = __float2bfloat16(v.y * scale * wv.y);
  o[2] = __float2bfloat16(v.z * scale * wv.z);
  o[3] = __float2bfloat16(v.w * scale * wv.w);
  *(uint2*)(xn + (size_t)row * DMODEL + t * 4) = *(const uint2*)o;
}

// ============ 256x256 8-phase bf16 MFMA GEMM, optional fused CE ============
// C[m][n] = sum_k A[m][k]*B[n][k]. A:[2048][1024], B:[VPAD2][1024] bf16.
// grid(8, NT256) (bm fastest for B-tile sharing), block 512 (8 waves, 2Mx4N).
// LDS: 2 buffers x {A-k0, B-k0, A-k1, B-k1} halves of 16KB each.
// Half layout: [256 rows][32 cols bf16] as 16 subtiles of [16][32] (1KB),
//   logical byte(r,c) = (r>>4)*1024 + (r&15)*64 + (c&31)*2, stored at
//   physical = logical ^ ((logical>>9)&1)<<5   (st_16x32 XOR swizzle, m201).
// Swizzle applied BOTH sides (rule #21): frag-read offset XORed, and the
// global_load_lds per-lane SOURCE col pre-swizzled; LDS dest stays linear.
template<bool WRITE_OUT, bool DO_CE>
__global__ __launch_bounds__(512, 2)
void k_gemm256(const bf16* __restrict__ A, const bf16* __restrict__ B,
               float* __restrict__ C, long ldc, int Nvalid,
               const int* __restrict__ targets, int shift,
               float* __restrict__ pmax, float* __restrict__ psum,
               float* __restrict__ ptgt, int ntiles) {
  __shared__ char lds[131072 + 9216];

  const int t = threadIdx.x;
  const int w = t >> 6, l = t & 63;
  const int g = l >> 4, q = l & 15;
  const int wr = w >> 2, wc = w & 3;
  const int bm = blockIdx.x, bn = blockIdx.y;

  f32x4 acc[8][4];
  #pragma unroll
  for (int i = 0; i < 8; ++i)
    #pragma unroll
    for (int j = 0; j < 4; ++j)
      #pragma unroll
      for (int r = 0; r < 4; ++r) acc[i][j][r] = 0.f;

  // staging source pointers (per-lane). Lane l writes LDS byte l*16 of its
  // subtile (linear DMA dest); pre-swizzled source col so that
  // LDS[physical] holds data for logical = physical ^ ((physical>>9)&1)<<5.
  const int srow = (l >> 2);                                // row in subtile
  const int scol = ((l & 3) * 8) ^ (((l >> 5) & 1) * 16);   // pre-swizzled col
  const bf16* gA0 = A + (size_t)(bm * 256 + (w * 2 + 0) * 16 + srow) * DMODEL + scol;
  const bf16* gA1 = A + (size_t)(bm * 256 + (w * 2 + 1) * 16 + srow) * DMODEL + scol;
  const bf16* gB0 = B + (size_t)(bn * 256 + (w * 2 + 0) * 16 + srow) * DMODEL + scol;
  const bf16* gB1 = B + (size_t)(bn * 256 + (w * 2 + 1) * 16 + srow) * DMODEL + scol;

  // stage half h (0=A-k0,1=B-k0,2=A-k1,3=B-k1) of K-tile tt into buffer buf
  auto stage = [&](int buf, int h, int tt) {
    const int kbase = tt * 64 + (h >> 1) * 32;
    char* lb = lds + buf * 65536 + (h >> 1) * 32768 + (h & 1) * 16384 + (w * 2) * 1024;
    if (h & 1) {
      gload_lds16(gB0 + kbase, lb);
      gload_lds16(gB1 + kbase, lb + 1024);
    } else {
      gload_lds16(gA0 + kbase, lb);
      gload_lds16(gA1 + kbase, lb + 1024);
    }
  };

  // within-subtile frag-read byte, st_16x32-swizzled (bit9 = q>=8)
  const int laneoff = (q * 64 + g * 16) ^ (((q >> 3) & 1) << 5);
  auto lda = [&](int buf, int kk, int mi) {
    return *(const bf16x8*)(lds + buf * 65536 + kk * 32768 + (wr * 8 + mi) * 1024 + laneoff);
  };
  auto ldb = [&](int buf, int kk, int ni) {
    return *(const bf16x8*)(lds + buf * 65536 + kk * 32768 + 16384 + (wc * 4 + ni) * 1024 + laneoff);
  };

  // ---- prologue: stage tile 0 fully; make k0-halves visible ----
  stage(0, 0, 0); stage(0, 1, 0); stage(0, 2, 0); stage(0, 3, 0);
  asm volatile("s_waitcnt vmcnt(4)" ::: "memory");
  __builtin_amdgcn_s_barrier();

  #define PHASE_MFMA(MH)                                                         \
    __builtin_amdgcn_s_barrier();                                                \
    __builtin_amdgcn_s_setprio(1);                                               \
    _Pragma("unroll")                                                            \
    for (int mi = 0; mi < 4; ++mi)                                               \
      _Pragma("unroll")                                                          \
      for (int ni = 0; ni < 4; ++ni)                                             \
        acc[(MH)*4 + mi][ni] = __builtin_amdgcn_mfma_f32_16x16x32_bf16(          \
            a[mi], b[ni], acc[(MH)*4 + mi][ni], 0, 0, 0);                        \
    __builtin_amdgcn_s_setprio(0);

  for (int tt = 0; tt < 16; ++tt) {
    const int buf = tt & 1, nbuf = buf ^ 1;
    const bool pre = tt < 15;
    bf16x8 a[4], b[4];

    // ---- P0: kk0, mi 0-3 ----
    #pragma unroll
    for (int mi = 0; mi < 4; ++mi) a[mi] = lda(buf, 0, mi);
    #pragma unroll
    for (int ni = 0; ni < 4; ++ni) b[ni] = ldb(buf, 0, ni);
    if (pre) stage(nbuf, 0, tt + 1);
    PHASE_MFMA(0)
    __builtin_amdgcn_s_barrier();

    // ---- P1: kk0, mi 4-7 ----
    #pragma unroll
    for (int mi = 0; mi < 4; ++mi) a[mi] = lda(buf, 0, 4 + mi);
    if (pre) stage(nbuf, 1, tt + 1);
    PHASE_MFMA(1)
    if (pre) asm volatile("s_waitcnt vmcnt(4)" ::: "memory");   // k1-halves(tt) landed
    else     asm volatile("s_waitcnt vmcnt(0)" ::: "memory");   // epilogue drain
    __builtin_amdgcn_s_barrier();

    // ---- P2: kk1, mi 0-3 ----
    #pragma unroll
    for (int mi = 0; mi < 4; ++mi) a[mi] = lda(buf, 1, mi);
    #pragma unroll
    for (int ni = 0; ni < 4; ++ni) b[ni] = ldb(buf, 1, ni);
    if (pre) stage(nbuf, 2, tt + 1);
    PHASE_MFMA(0)
    __builtin_amdgcn_s_barrier();

    // ---- P3: kk1, mi 4-7 ----
    #pragma unroll
    for (int mi = 0; mi < 4; ++mi) a[mi] = lda(buf, 1, 4 + mi);
    if (pre) stage(nbuf, 3, tt + 1);
    PHASE_MFMA(1)
    if (pre) asm volatile("s_waitcnt vmcnt(4)" ::: "memory");   // k0-halves(tt+1) landed
    __builtin_amdgcn_s_barrier();
  }
  #undef PHASE_MFMA

  // ---------------- epilogue ----------------
  if constexpr (WRITE_OUT) {
    #pragma unroll
    for (int mi = 0; mi < 8; ++mi) {
      #pragma unroll
      for (int r = 0; r < 4; ++r) {
        const long row = bm * 256 + wr * 128 + mi * 16 + g * 4 + r;
        #pragma unroll
        for (int ni = 0; ni < 4; ++ni) {
          const int col = bn * 256 + wc * 64 + ni * 16 + q;
          if (col < Nvalid) C[row * ldc + col] = acc[mi][ni][r];
        }
      }
    }
  }

  if constexpr (DO_CE) {
    float* lds_m = (float*)(lds + 131072);   // [256][4]
    float* lds_s = lds_m + 1024;             // [256][4]
    int* lds_tgt = (int*)(lds_s + 1024);     // [256]
    if (t < 256) {
      const int rowg = bm * 256 + t;
      lds_tgt[t] = (rowg < S_LEN - shift) ? targets[rowg + shift] : -1;
    }
    __syncthreads();
    #pragma unroll
    for (int mi = 0; mi < 8; ++mi) {
      #pragma unroll
      for (int r = 0; r < 4; ++r) {
        const int rl = wr * 128 + mi * 16 + g * 4 + r;
        const int tgt = lds_tgt[rl];
        float v[4];
        #pragma unroll
        for (int ni = 0; ni < 4; ++ni) {
          const int n = bn * 256 + wc * 64 + ni * 16 + q;
          const float av = acc[mi][ni][r];
          if (n == tgt) ptgt[bm * 256 + rl] = av;
          v[ni] = (n < Nvalid) ? av : -1e30f;
        }
        float m = fmaxf(fmaxf(v[0], v[1]), fmaxf(v[2], v[3]));
        #pragma unroll
        for (int d = 1; d < 16; d <<= 1) m = fmaxf(m, __shfl_xor(m, d, 64));
        float s = 0.f;
        #pragma unroll
        for (int ni = 0; ni < 4; ++ni) s += __expf(v[ni] - m);
        #pragma unroll
        for (int d = 1; d < 16; d <<= 1) s += __shfl_xor(s, d, 64);
        if (q == 0) { lds_m[rl * 4 + wc] = m; lds_s[rl * 4 + wc] = s; }
      }
    }
    __syncthreads();
    if (t < 256) {
      float M = lds_m[t * 4 + 0], Ssum = lds_s[t * 4 + 0];
      #pragma unroll
      for (int c = 1; c < 4; ++c) {
        const float m2 = lds_m[t * 4 + c], s2 = lds_s[t * 4 + c];
        const float nM = fmaxf(M, m2);
        Ssum = Ssum * __expf(M - nM) + s2 * __expf(m2 - nM);
        M = nM;
      }
      const size_t idx = (size_t)(bm * 256 + t) * ntiles + bn;
      pmax[idx] = M;
      psum[idx] = Ssum;
    }
  }
}

// ---------------- 128x128 GEMM (kept for the small d->d projection) ----------------
__global__ __launch_bounds__(256, 2)
void k_gemm(const bf16* __restrict__ A, const bf16* __restrict__ B,
            float* __restrict__ C, long ldc, int Nvalid) {
  constexpr int K = DMODEL;
  __shared__ bf16 As[128 * 32];
  __shared__ bf16 Bs[128 * 32];

  const int t = threadIdx.x;
  const int bn = blockIdx.x, bm = blockIdx.y;
  const int w = t >> 6, l = t & 63, g = l >> 4, q = l & 15;
  const int wr = w >> 1, wc = w & 1;

  f32x4 acc[4][4];
  #pragma unroll
  for (int i = 0; i < 4; ++i)
    #pragma unroll
    for (int j = 0; j < 4; ++j)
      #pragma unroll
      for (int r = 0; r < 4; ++r) acc[i][j][r] = 0.f;

  char* lA0 = (char*)As + w * 1024;
  char* lA1 = (char*)As + 4096 + w * 1024;
  char* lB0 = (char*)Bs + w * 1024;
  char* lB1 = (char*)Bs + 4096 + w * 1024;
  const char* gA0 = (const char*)(A + (size_t)(bm * 128 + (t >> 2)) * K) + (t & 3) * 16;
  const char* gA1 = gA0 + (size_t)64 * K * 2;
  const char* gB0 = (const char*)(B + (size_t)(bn * 128 + (t >> 2)) * K) + (t & 3) * 16;
  const char* gB1 = gB0 + (size_t)64 * K * 2;

  for (int k0 = 0; k0 < K; k0 += 32) {
    const int kb = k0 * 2;
    gload_lds16(gA0 + kb, lA0);
    gload_lds16(gA1 + kb, lA1);
    gload_lds16(gB0 + kb, lB0);
    gload_lds16(gB1 + kb, lB1);
    __syncthreads();
    bf16x8 a[4], b[4];
    #pragma unroll
    for (int mi = 0; mi < 4; ++mi)
      a[mi] = *(const bf16x8*)&As[(wr * 64 + mi * 16 + q) * 32 + g * 8];
    #pragma unroll
    for (int ni = 0; ni < 4; ++ni)
      b[ni] = *(const bf16x8*)&Bs[(wc * 64 + ni * 16 + q) * 32 + g * 8];
    #pragma unroll
    for (int mi = 0; mi < 4; ++mi)
      #pragma unroll
      for (int ni = 0; ni < 4; ++ni)
        acc[mi][ni] = __builtin_amdgcn_mfma_f32_16x16x32_bf16(a[mi], b[ni], acc[mi][ni], 0, 0, 0);
    __syncthreads();
  }

  #pragma unroll
  for (int mi = 0; mi < 4; ++mi) {
    #pragma unroll
    for (int r = 0; r < 4; ++r) {
      const long row = bm * 128 + wr * 64 + mi * 16 + g * 4 + r;
      #pragma unroll
      for (int ni = 0; ni < 4; ++ni) {
        const int col = bn * 128 + wc * 64 + ni * 16 + q;
        if (col < Nvalid) C[row * ldc + col] = acc[mi][ni][r];
      }
    }
  }
}

// ---------------- combine per-row partials -> NLL ----------------
__global__ __launch_bounds__(64) void k_combine(const float* __restrict__ pmax,
                                                const float* __restrict__ psum,
                                                const float* __restrict__ ptgt,
                                                float* __restrict__ nll,
                                                int ntiles, int nv) {
  const int r = blockIdx.x;
  const int l = threadIdx.x;
  float M = -1e30f, Ssum = 0.f;
  for (int tl = l; tl < ntiles; tl += 64) {
    const float m = pmax[(size_t)r * ntiles + tl];
    const float s = psum[(size_t)r * ntiles + tl];
    const float nM = fmaxf(M, m);
    Ssum = Ssum * __expf(M - nM) + s * __expf(m - nM);
    M = nM;
  }
  #pragma unroll
  for (int d = 1; d < 64; d <<= 1) {
    const float m2 = __shfl_xor(M, d, 64);
    const float s2 = __shfl_xor(Ssum, d, 64);
    const float nM = fmaxf(M, m2);
    Ssum = Ssum * __expf(M - nM) + s2 * __expf(m2 - nM);
    M = nM;
  }
  if (l == 0) nll[r] = (r < nv) ? (M + logf(Ssum) - ptgt[r]) : 0.f;
}

// ---------------- final loss ----------------
__global__ __launch_bounds__(256) void k_loss(const float* __restrict__ nll,
                                              float* __restrict__ out) {
  __shared__ float sh[256];
  const int t = threadIdx.x;
  float sums[3];
  #pragma unroll
  for (int h = 0; h < 3; ++h) {
    const int nv = 2047 - h;
    float s = 0.f;
    for (int r = t; r < nv; r += 256) s += nll[h * 2048 + r];
    sh[t] = s; __syncthreads();
    for (int off = 128; off > 0; off >>= 1) {
      if (t < off) sh[t] += sh[t + off];
      __syncthreads();
    }
    sums[h] = sh[0]; __syncthreads();
  }
  if (t == 0)
    out[0] = sums[0] / 2047.f + 0.3f * 0.5f * (sums[1] / 2046.f + sums[2] / 2045.f);
}

extern "C" void kernel_launch(void* const* d_in, const int* in_sizes, int n_in,
                              void* d_out, int out_size, void* d_ws, size_t ws_size,
                              hipStream_t stream) {
  const float* hidden      = (const float*)d_in[0];
  const int*   targets     = (const int*)d_in[1];
  const float* emb_w       = (const float*)d_in[2];
  const float* main_norm_w = (const float*)d_in[3];
  const float* aux_proj_w  = (const float*)d_in[4];
  const float* aux_norm_w  = (const float*)d_in[5];
  const float* aux_out_w   = (const float*)d_in[6];
  float* out = (float*)d_out;

  char* ws = (char*)d_ws;
  // workspace layout
  bf16*  Wb    = (bf16*)(ws);                   // [VPAD2][1024] bf16, 103,284,736 B
  bf16*  hb    = (bf16*)(ws + 103284736);       // hidden bf16, 4 MiB
  bf16*  xn    = (bf16*)(ws + 107479040);       // normalized input bf16, 4 MiB
  bf16*  projb = (bf16*)(ws + 111673344);       // aux proj weights bf16, 4 MiB
  float* hbuf  = (float*)(ws + 115867648);      // aux pre-norm f32, 8 MiB
  float* pmax  = (float*)(ws + 124256256);      // [2048][197]
  float* psum  = (float*)(ws + 125870080);      // [2048][197]
  float* ptgt  = (float*)(ws + 127483904);      // [2048]
  float* nll   = (float*)(ws + 127492096);      // [3][2048]

  // prep
  k_cvt<<<2048, 256, 0, stream>>>(hidden, hb, 2048, 2048);
  k_cvt<<<2048, 256, 0, stream>>>(aux_proj_w, projb, 2048, 2048);
  k_rms<<<2048, 256, 0, stream>>>(hidden, main_norm_w, xn);

  // ---- main head ----
  k_cvt<<<2048, 256, 0, stream>>>(emb_w, Wb, VOCAB, VPAD2);
  k_gemm256<true, true><<<dim3(8, NT256), 512, 0, stream>>>(
      xn, Wb, out, VOCAB, VOCAB, targets, 1, pmax, psum, ptgt, NT256);
  k_combine<<<2048, 64, 0, stream>>>(pmax, psum, ptgt, nll, NT256, 2047);

  // ---- aux heads ----
  for (int i = 0; i < 2; ++i) {
    k_cvt<<<2048, 256, 0, stream>>>(aux_out_w + (size_t)i * VOCAB * DMODEL, Wb, VOCAB, VPAD2);
    k_gemm<<<dim3(8, 16), 256, 0, stream>>>(
        hb, projb + (size_t)i * DMODEL * DMODEL, hbuf, DMODEL, DMODEL);
    k_rms<<<2048, 256, 0, stream>>>(hbuf, aux_norm_w + (size_t)i * DMODEL, xn);
    k_gemm256<false, true><<<dim3(8, NT256), 512, 0, stream>>>(
        xn, Wb, nullptr, 0, VOCAB, targets, i + 2, pmax, psum, ptgt, NT256);
    k_combine<<<2048, 64, 0, stream>>>(pmax, psum, ptgt, nll + (i + 1) * 2048, NT256, 2048 - (i + 2));
  }

  k_loss<<<1, 256, 0, stream>>>(nll, out + (size_t)S_LEN * VOCAB);
}

// Round 4
// 1205.278 us; speedup vs baseline: 1.0285x; 1.0027x over previous
//
#include <hip/hip_runtime.h>
#include <hip/hip_bf16.h>

// MultiTokenPrediction: main head logits + fused CE for main + 2 aux heads.
// B=1, S=2048, D=1024, V=50257, heads predict t+1 (main), t+2, t+3 (aux).

typedef __hip_bfloat16 bf16;
typedef __attribute__((ext_vector_type(8))) short bf16x8;
typedef __attribute__((ext_vector_type(4))) float f32x4;

typedef const __attribute__((address_space(1))) void* gptr_t;
typedef __attribute__((address_space(3))) void* lptr_t;

#define S_LEN   2048
#define DMODEL  1024
#define VOCAB   50257
#define VPAD2   51200   // 200*256 (pad so 8x8x25 block swizzle is bijective)
#define NT256   200     // VPAD2/256

__device__ __forceinline__ void gload_lds16(const void* g, void* l) {
  __builtin_amdgcn_global_load_lds((gptr_t)g, (lptr_t)l, 16, 0, 0);
}

// ---------------- f32 -> bf16 conversion with row zero-padding ----------------
__global__ __launch_bounds__(256) void k_cvt(const float* __restrict__ src,
                                             bf16* __restrict__ dst,
                                             long rows_src, long rows_pad) {
  const long total4 = rows_pad << 8;  // rows_pad * 1024 / 4
  for (long i = (long)blockIdx.x * 256 + threadIdx.x; i < total4;
       i += (long)gridDim.x * 256) {
    const long e = i << 2;
    const long row = e >> 10;
    alignas(8) bf16 o[4];
    if (row < rows_src) {
      const float4 v = *(const float4*)(src + e);
      o[0] = __float2bfloat16(v.x); o[1] = __float2bfloat16(v.y);
      o[2] = __float2bfloat16(v.z); o[3] = __float2bfloat16(v.w);
    } else {
      o[0] = o[1] = o[2] = o[3] = __float2bfloat16(0.f);
    }
    *(uint2*)(dst + e) = *(const uint2*)o;
  }
}

// ---------------- RMSNorm row kernel: f32 in, bf16 out ----------------
__global__ __launch_bounds__(256) void k_rms(const float* __restrict__ x,
                                             const float* __restrict__ w,
                                             bf16* __restrict__ xn) {
  const int row = blockIdx.x;
  const int t = threadIdx.x;
  const float4 v = ((const float4*)(x + (size_t)row * DMODEL))[t];
  float ss = v.x*v.x + v.y*v.y + v.z*v.z + v.w*v.w;
  #pragma unroll
  for (int d = 1; d < 64; d <<= 1) ss += __shfl_xor(ss, d, 64);
  __shared__ float red[4];
  if ((t & 63) == 0) red[t >> 6] = ss;
  __syncthreads();
  const float tot = red[0] + red[1] + red[2] + red[3];
  const float scale = rsqrtf(tot * (1.f / DMODEL) + 1e-5f);
  const float4 wv = ((const float4*)w)[t];
  alignas(8) bf16 o[4];
  o[0] = __float2bfloat16(v.x * scale * wv.x);
  o[1] = __float2bfloat16(v.y * scale * wv.y);
  o[2] = __float2bfloat16(v.z * scale * wv.z);
  o[3] = __float2bfloat16(v.w * scale * wv.w);
  *(uint2*)(xn + (size_t)row * DMODEL + t * 4) = *(const uint2*)o;
}

// ============ 256x256 8-phase bf16 MFMA GEMM, optional fused CE ============
// C[m][n] = sum_k A[m][k]*B[n][k]. A:[2048][1024], B:[VPAD2][1024] bf16.
// grid(1600): id -> bm=(id>>3)&7, bn=(id&7)+8*(id>>6)  — the 8 bm-siblings of
// a bn-tile share id mod 8 -> same XCD under round-robin dispatch (B L2-shared).
// block 512 (8 waves, 2Mx4N). LDS: 2 bufs x {A-k0,B-k0,A-k1,B-k1} 16KB halves.
// Half layout: [256r][32c bf16] as 16 [16][32] subtiles (1KB), logical byte
// (r,c) = (r>>4)*1024+(r&15)*64+c*2, stored physical = logical^((logical>>9)&1)<<5
// (st_16x32 swizzle). Swizzle on BOTH sides: frag-read offset XORed, DMA source
// col pre-swizzled, LDS DMA dest linear (rule #21). Verified conflict-free (R3).
// K-loop fully compile-time: ds_reads = 1 base VGPR + offset: immediates;
// global srcs = 4 bumped pointers + <=320B immediates.
template<bool WRITE_OUT, bool DO_CE>
__global__ __launch_bounds__(512, 2)
void k_gemm256(const bf16* __restrict__ A, const bf16* __restrict__ B,
               float* __restrict__ C, long ldc, int Nvalid,
               const int* __restrict__ targets, int shift,
               float* __restrict__ pmax, float* __restrict__ psum,
               float* __restrict__ ptgt, int ntiles) {
  __shared__ char lds[131072 + 9216];

  const int t = threadIdx.x;
  const int w = t >> 6, l = t & 63;
  const int g = l >> 4, q = l & 15;
  const int wr = w >> 2, wc = w & 3;
  const int id = blockIdx.x;
  const int bm = (id >> 3) & 7;
  const int bn = (id & 7) + ((id >> 6) << 3);

  f32x4 acc[8][4];
  #pragma unroll
  for (int i = 0; i < 8; ++i)
    #pragma unroll
    for (int j = 0; j < 4; ++j)
      #pragma unroll
      for (int r = 0; r < 4; ++r) acc[i][j][r] = 0.f;

  // ---- staging source pointers (per-lane), bumped +256B per 2 K-tiles ----
  const int srow = (l >> 2);                                // row in subtile
  const int scol = ((l & 3) * 8) ^ (((l >> 5) & 1) * 16);   // pre-swizzled col
  const char* gA0 = (const char*)(A + (size_t)(bm * 256 + (w * 2 + 0) * 16 + srow) * DMODEL + scol);
  const char* gA1 = (const char*)(A + (size_t)(bm * 256 + (w * 2 + 1) * 16 + srow) * DMODEL + scol);
  const char* gB0 = (const char*)(B + (size_t)(bn * 256 + (w * 2 + 0) * 16 + srow) * DMODEL + scol);
  const char* gB1 = (const char*)(B + (size_t)(bn * 256 + (w * 2 + 1) * 16 + srow) * DMODEL + scol);

  // ---- ds_read bases (one VGPR each; everything else is offset: immediate) ----
  const int laneoff = (q * 64 + g * 16) ^ (((q >> 3) & 1) << 5);
  const char* rdA = lds + wr * 8192 + laneoff;
  const char* rdB = lds + 16384 + wc * 4096 + laneoff;

#define RDA(BUF, KK, MI) (*(const bf16x8*)(rdA + (BUF)*65536 + (KK)*32768 + (MI)*1024))
#define RDB(BUF, KK, NI) (*(const bf16x8*)(rdB + (BUF)*65536 + (KK)*32768 + (NI)*1024))

  // stage half H (0=A-k0,1=B-k0,2=A-k1,3=B-k1) at byte offset KOFF from the
  // current pointers into buffer BUF. Wave w fills subtiles w*2, w*2+1.
#define STAGE(BUF, H, KOFF) do {                                                  \
    char* lb_ = lds + (BUF)*65536 + ((H)>>1)*32768 + ((H)&1)*16384 + w * 2048;    \
    const char* s0_ = ((H)&1) ? gB0 : gA0;                                        \
    const char* s1_ = ((H)&1) ? gB1 : gA1;                                        \
    gload_lds16(s0_ + (KOFF) + ((H)>>1)*64, lb_);                                 \
    gload_lds16(s1_ + (KOFF) + ((H)>>1)*64, lb_ + 1024);                          \
  } while (0)

#define PH_MFMA(MH)                                                               \
    __builtin_amdgcn_s_barrier();                                                 \
    __builtin_amdgcn_s_setprio(1);                                                \
    _Pragma("unroll")                                                             \
    for (int mi_ = 0; mi_ < 4; ++mi_)                                             \
      _Pragma("unroll")                                                           \
      for (int ni_ = 0; ni_ < 4; ++ni_)                                           \
        acc[(MH)*4 + mi_][ni_] = __builtin_amdgcn_mfma_f32_16x16x32_bf16(         \
            a[mi_], b[ni_], acc[(MH)*4 + mi_][ni_], 0, 0, 0);                     \
    __builtin_amdgcn_s_setprio(0);

  // One K-tile (64 cols) = 4 phases. BUF compile-time; stages tile+1 into BUF^1.
#define TILE(BUF, DOSTG, KOFF, LAST) do {                                         \
    bf16x8 a[4], b[4];                                                            \
    _Pragma("unroll") for (int mi_ = 0; mi_ < 4; ++mi_) a[mi_] = RDA(BUF, 0, mi_);\
    _Pragma("unroll") for (int ni_ = 0; ni_ < 4; ++ni_) b[ni_] = RDB(BUF, 0, ni_);\
    if (DOSTG) STAGE(1-(BUF), 0, KOFF);                                           \
    PH_MFMA(0)                                                                    \
    __builtin_amdgcn_s_barrier();                                                 \
    _Pragma("unroll") for (int mi_ = 0; mi_ < 4; ++mi_) a[mi_] = RDA(BUF, 0, 4+mi_);\
    if (DOSTG) STAGE(1-(BUF), 1, KOFF);                                           \
    PH_MFMA(1)                                                                    \
    if (DOSTG) { asm volatile("s_waitcnt vmcnt(4)" ::: "memory"); }               \
    if (LAST)  { asm volatile("s_waitcnt vmcnt(0)" ::: "memory"); }               \
    __builtin_amdgcn_s_barrier();                                                 \
    _Pragma("unroll") for (int mi_ = 0; mi_ < 4; ++mi_) a[mi_] = RDA(BUF, 1, mi_);\
    _Pragma("unroll") for (int ni_ = 0; ni_ < 4; ++ni_) b[ni_] = RDB(BUF, 1, ni_);\
    if (DOSTG) STAGE(1-(BUF), 2, KOFF);                                           \
    PH_MFMA(0)                                                                    \
    __builtin_amdgcn_s_barrier();                                                 \
    _Pragma("unroll") for (int mi_ = 0; mi_ < 4; ++mi_) a[mi_] = RDA(BUF, 1, 4+mi_);\
    if (DOSTG) STAGE(1-(BUF), 3, KOFF);                                           \
    PH_MFMA(1)                                                                    \
    if (DOSTG) { asm volatile("s_waitcnt vmcnt(4)" ::: "memory"); }               \
    __builtin_amdgcn_s_barrier();                                                 \
  } while (0)

  // ---- prologue: stage tile 0 into buf0; wait for its k0-halves ----
  STAGE(0, 0, 0); STAGE(0, 1, 0); STAGE(0, 2, 0); STAGE(0, 3, 0);
  asm volatile("s_waitcnt vmcnt(4)" ::: "memory");
  __builtin_amdgcn_s_barrier();

  // ---- main loop: 16 K-tiles, 2 per iteration (buf parity compile-time) ----
  for (int t2 = 0; t2 < 7; ++t2) {
    TILE(0, 1, 128, 0);   // tile 2*t2   (buf0), stages tile 2*t2+1
    TILE(1, 1, 256, 0);   // tile 2*t2+1 (buf1), stages tile 2*t2+2
    gA0 += 256; gA1 += 256; gB0 += 256; gB1 += 256;
  }
  TILE(0, 1, 128, 0);     // tile 14, stages tile 15
  TILE(1, 0, 0, 1);       // tile 15, drain

#undef TILE
#undef PH_MFMA
#undef STAGE
#undef RDA
#undef RDB

  // ---------------- epilogue ----------------
  if constexpr (WRITE_OUT) {
    #pragma unroll
    for (int mi = 0; mi < 8; ++mi) {
      #pragma unroll
      for (int r = 0; r < 4; ++r) {
        const long row = bm * 256 + wr * 128 + mi * 16 + g * 4 + r;
        #pragma unroll
        for (int ni = 0; ni < 4; ++ni) {
          const int col = bn * 256 + wc * 64 + ni * 16 + q;
          if (col < Nvalid) C[row * ldc + col] = acc[mi][ni][r];
        }
      }
    }
  }

  if constexpr (DO_CE) {
    float* lds_m = (float*)(lds + 131072);   // [256][4]
    float* lds_s = lds_m + 1024;             // [256][4]
    int* lds_tgt = (int*)(lds_s + 1024);     // [256]
    if (t < 256) {
      const int rowg = bm * 256 + t;
      lds_tgt[t] = (rowg < S_LEN - shift) ? targets[rowg + shift] : -1;
    }
    __syncthreads();
    #pragma unroll
    for (int mi = 0; mi < 8; ++mi) {
      #pragma unroll
      for (int r = 0; r < 4; ++r) {
        const int rl = wr * 128 + mi * 16 + g * 4 + r;
        const int tgt = lds_tgt[rl];
        float v[4];
        #pragma unroll
        for (int ni = 0; ni < 4; ++ni) {
          const int n = bn * 256 + wc * 64 + ni * 16 + q;
          const float av = acc[mi][ni][r];
          if (n == tgt) ptgt[bm * 256 + rl] = av;
          v[ni] = (n < Nvalid) ? av : -1e30f;
        }
        float m = fmaxf(fmaxf(v[0], v[1]), fmaxf(v[2], v[3]));
        #pragma unroll
        for (int d = 1; d < 16; d <<= 1) m = fmaxf(m, __shfl_xor(m, d, 64));
        float s = 0.f;
        #pragma unroll
        for (int ni = 0; ni < 4; ++ni) s += __expf(v[ni] - m);
        #pragma unroll
        for (int d = 1; d < 16; d <<= 1) s += __shfl_xor(s, d, 64);
        if (q == 0) { lds_m[rl * 4 + wc] = m; lds_s[rl * 4 + wc] = s; }
      }
    }
    __syncthreads();
    if (t < 256) {
      float M = lds_m[t * 4 + 0], Ssum = lds_s[t * 4 + 0];
      #pragma unroll
      for (int c = 1; c < 4; ++c) {
        const float m2 = lds_m[t * 4 + c], s2 = lds_s[t * 4 + c];
        const float nM = fmaxf(M, m2);
        Ssum = Ssum * __expf(M - nM) + s2 * __expf(m2 - nM);
        M = nM;
      }
      const size_t idx = (size_t)(bm * 256 + t) * ntiles + bn;
      pmax[idx] = M;
      psum[idx] = Ssum;
    }
  }
}

// ---------------- 128x128 GEMM (kept for the small d->d projection) ----------------
__global__ __launch_bounds__(256, 2)
void k_gemm(const bf16* __restrict__ A, const bf16* __restrict__ B,
            float* __restrict__ C, long ldc, int Nvalid) {
  constexpr int K = DMODEL;
  __shared__ bf16 As[128 * 32];
  __shared__ bf16 Bs[128 * 32];

  const int t = threadIdx.x;
  const int bn = blockIdx.x, bm = blockIdx.y;
  const int w = t >> 6, l = t & 63, g = l >> 4, q = l & 15;
  const int wr = w >> 1, wc = w & 1;

  f32x4 acc[4][4];
  #pragma unroll
  for (int i = 0; i < 4; ++i)
    #pragma unroll
    for (int j = 0; j < 4; ++j)
      #pragma unroll
      for (int r = 0; r < 4; ++r) acc[i][j][r] = 0.f;

  char* lA0 = (char*)As + w * 1024;
  char* lA1 = (char*)As + 4096 + w * 1024;
  char* lB0 = (char*)Bs + w * 1024;
  char* lB1 = (char*)Bs + 4096 + w * 1024;
  const char* gA0 = (const char*)(A + (size_t)(bm * 128 + (t >> 2)) * K) + (t & 3) * 16;
  const char* gA1 = gA0 + (size_t)64 * K * 2;
  const char* gB0 = (const char*)(B + (size_t)(bn * 128 + (t >> 2)) * K) + (t & 3) * 16;
  const char* gB1 = gB0 + (size_t)64 * K * 2;

  for (int k0 = 0; k0 < K; k0 += 32) {
    const int kb = k0 * 2;
    gload_lds16(gA0 + kb, lA0);
    gload_lds16(gA1 + kb, lA1);
    gload_lds16(gB0 + kb, lB0);
    gload_lds16(gB1 + kb, lB1);
    __syncthreads();
    bf16x8 a[4], b[4];
    #pragma unroll
    for (int mi = 0; mi < 4; ++mi)
      a[mi] = *(const bf16x8*)&As[(wr * 64 + mi * 16 + q) * 32 + g * 8];
    #pragma unroll
    for (int ni = 0; ni < 4; ++ni)
      b[ni] = *(const bf16x8*)&Bs[(wc * 64 + ni * 16 + q) * 32 + g * 8];
    #pragma unroll
    for (int mi = 0; mi < 4; ++mi)
      #pragma unroll
      for (int ni = 0; ni < 4; ++ni)
        acc[mi][ni] = __builtin_amdgcn_mfma_f32_16x16x32_bf16(a[mi], b[ni], acc[mi][ni], 0, 0, 0);
    __syncthreads();
  }

  #pragma unroll
  for (int mi = 0; mi < 4; ++mi) {
    #pragma unroll
    for (int r = 0; r < 4; ++r) {
      const long row = bm * 128 + wr * 64 + mi * 16 + g * 4 + r;
      #pragma unroll
      for (int ni = 0; ni < 4; ++ni) {
        const int col = bn * 128 + wc * 64 + ni * 16 + q;
        if (col < Nvalid) C[row * ldc + col] = acc[mi][ni][r];
      }
    }
  }
}

// ---------------- combine per-row partials -> NLL ----------------
__global__ __launch_bounds__(64) void k_combine(const float* __restrict__ pmax,
                                                const float* __restrict__ psum,
                                                const float* __restrict__ ptgt,
                                                float* __restrict__ nll,
                                                int ntiles, int nv) {
  const int r = blockIdx.x;
  const int l = threadIdx.x;
  float M = -1e30f, Ssum = 0.f;
  for (int tl = l; tl < ntiles; tl += 64) {
    const float m = pmax[(size_t)r * ntiles + tl];
    const float s = psum[(size_t)r * ntiles + tl];
    const float nM = fmaxf(M, m);
    Ssum = Ssum * __expf(M - nM) + s * __expf(m - nM);
    M = nM;
  }
  #pragma unroll
  for (int d = 1; d < 64; d <<= 1) {
    const float m2 = __shfl_xor(M, d, 64);
    const float s2 = __shfl_xor(Ssum, d, 64);
    const float nM = fmaxf(M, m2);
    Ssum = Ssum * __expf(M - nM) + s2 * __expf(m2 - nM);
    M = nM;
  }
  if (l == 0) nll[r] = (r < nv) ? (M + logf(Ssum) - ptgt[r]) : 0.f;
}

// ---------------- final loss ----------------
__global__ __launch_bounds__(256) void k_loss(const float* __restrict__ nll,
                                              float* __restrict__ out) {
  __shared__ float sh[256];
  const int t = threadIdx.x;
  float sums[3];
  #pragma unroll
  for (int h = 0; h < 3; ++h) {
    const int nv = 2047 - h;
    float s = 0.f;
    for (int r = t; r < nv; r += 256) s += nll[h * 2048 + r];
    sh[t] = s; __syncthreads();
    for (int off = 128; off > 0; off >>= 1) {
      if (t < off) sh[t] += sh[t + off];
      __syncthreads();
    }
    sums[h] = sh[0]; __syncthreads();
  }
  if (t == 0)
    out[0] = sums[0] / 2047.f + 0.3f * 0.5f * (sums[1] / 2046.f + sums[2] / 2045.f);
}

extern "C" void kernel_launch(void* const* d_in, const int* in_sizes, int n_in,
                              void* d_out, int out_size, void* d_ws, size_t ws_size,
                              hipStream_t stream) {
  const float* hidden      = (const float*)d_in[0];
  const int*   targets     = (const int*)d_in[1];
  const float* emb_w       = (const float*)d_in[2];
  const float* main_norm_w = (const float*)d_in[3];
  const float* aux_proj_w  = (const float*)d_in[4];
  const float* aux_norm_w  = (const float*)d_in[5];
  const float* aux_out_w   = (const float*)d_in[6];
  float* out = (float*)d_out;

  char* ws = (char*)d_ws;
  // workspace layout (256B aligned)
  bf16*  Wb    = (bf16*)(ws);                   // [VPAD2][1024] bf16, 104,857,600 B
  bf16*  hb    = (bf16*)(ws + 104857600);       // hidden bf16, 4 MiB
  bf16*  xn    = (bf16*)(ws + 109051904);       // normalized input bf16, 4 MiB
  bf16*  projb = (bf16*)(ws + 113246208);       // aux proj weights bf16, 4 MiB
  float* hbuf  = (float*)(ws + 117440512);      // aux pre-norm f32, 8 MiB
  float* pmax  = (float*)(ws + 125829120);      // [2048][200]
  float* psum  = (float*)(ws + 127467520);      // [2048][200]
  float* ptgt  = (float*)(ws + 129105920);      // [2048]
  float* nll   = (float*)(ws + 129114112);      // [3][2048]

  // prep
  k_cvt<<<2048, 256, 0, stream>>>(hidden, hb, 2048, 2048);
  k_cvt<<<2048, 256, 0, stream>>>(aux_proj_w, projb, 2048, 2048);
  k_rms<<<2048, 256, 0, stream>>>(hidden, main_norm_w, xn);

  // ---- main head ----
  k_cvt<<<2048, 256, 0, stream>>>(emb_w, Wb, VOCAB, VPAD2);
  k_gemm256<true, true><<<1600, 512, 0, stream>>>(
      xn, Wb, out, VOCAB, VOCAB, targets, 1, pmax, psum, ptgt, NT256);
  k_combine<<<2048, 64, 0, stream>>>(pmax, psum, ptgt, nll, NT256, 2047);

  // ---- aux heads ----
  for (int i = 0; i < 2; ++i) {
    k_cvt<<<2048, 256, 0, stream>>>(aux_out_w + (size_t)i * VOCAB * DMODEL, Wb, VOCAB, VPAD2);
    k_gemm<<<dim3(8, 16), 256, 0, stream>>>(
        hb, projb + (size_t)i * DMODEL * DMODEL, hbuf, DMODEL, DMODEL);
    k_rms<<<2048, 256, 0, stream>>>(hbuf, aux_norm_w + (size_t)i * DMODEL, xn);
    k_gemm256<false, true><<<1600, 512, 0, stream>>>(
        xn, Wb, nullptr, 0, VOCAB, targets, i + 2, pmax, psum, ptgt, NT256);
    k_combine<<<2048, 64, 0, stream>>>(pmax, psum, ptgt, nll + (i + 1) * 2048, NT256, 2048 - (i + 2));
  }

  k_loss<<<1, 256, 0, stream>>>(nll, out + (size_t)S_LEN * VOCAB);
}